// Round 8
// baseline (181.889 us; speedup 1.0000x reference)
//
#include <hip/hip_runtime.h>
#include <math.h>

#define S 4096
#define B 16
#define CK 256          // tile cols
#define NCHUNK (S / CK) // 16
#define NB 4            // LDS buffers (depth-3 pipeline)
#define R 8             // attention rows per wave

// ---------------------------------------------------------------------------
// Fused QKV skinny GEMM — deep async pipeline (T3+T4: counted vmcnt).
// Grid: 768 blocks = 3 mats x 256 groups(16 rows x 16 batches), 1 block/CU
// (128 KB LDS). Tiles 0..2 prefetched; steady state keeps 3 tiles (24 DMAs,
// 96 KB) in flight per block; vmcnt(24) retires exactly the oldest tile.
// R6 failed because vmcnt(0) drained the just-issued prefetch too (m218's
// "drain0 == no pipeline"). Raw s_barrier (NOT __syncthreads — hipcc inserts
// vmcnt(0) before it). Two barriers/iter: 2nd fences LDS-buffer reuse.
// ---------------------------------------------------------------------------
__global__ __launch_bounds__(256, 1) void qkv_kernel(
    const float* __restrict__ x,
    const float* __restrict__ Wq, const float* __restrict__ bq,
    const float* __restrict__ Wk, const float* __restrict__ bk,
    const float* __restrict__ Wv, const float* __restrict__ bv,
    float* __restrict__ q, float* __restrict__ k, float* __restrict__ v)
{
    __shared__ float wbuf[NB][16 * CK];   // 4 x 16 KB
    __shared__ float xbuf[NB][B * CK];    // 4 x 16 KB  (128 KB total)

    const int tid  = threadIdx.x;
    const int lane = tid & 63;
    const int wave = tid >> 6;
    const int bx   = blockIdx.x;        // 0..767
    const int mat  = bx >> 8;           // 0:q 1:k 2:v
    const int og   = bx & 255;          // 16-row group
    const int o0   = og * 16;

    const float* W    = (mat == 0) ? Wq : (mat == 1) ? Wk : Wv;
    const float* bias = (mat == 0) ? bq : (mat == 1) ? bk : bv;
    float*       out  = (mat == 0) ? q  : (mat == 1) ? k  : v;

    float acc[4][16];
    #pragma unroll
    for (int r = 0; r < 4; ++r)
        #pragma unroll
        for (int b = 0; b < 16; ++b) acc[r][b] = 0.f;

    // Stage tile c into buffer bufi (8 DMAs per wave, 32 per block = 32 KB).
    // LDS dst is wave-uniform (HW adds lane*16B); global src is per-lane.
    #define QKV_STAGE(bufi, c)                                                \
    {                                                                         \
        _Pragma("unroll")                                                     \
        for (int j = 0; j < 4; ++j) {                                         \
            const int row = j * 4 + wave;                                     \
            const float* gw = &W[(size_t)(o0 + row) * S + (c) * CK + lane*4]; \
            __builtin_amdgcn_global_load_lds(                                 \
                (const __attribute__((address_space(1))) void*)gw,            \
                (__attribute__((address_space(3))) void*)&wbuf[bufi][row*CK], \
                16, 0, 0);                                                    \
            const float* gx = &x[(size_t)row * S + (c) * CK + lane * 4];      \
            __builtin_amdgcn_global_load_lds(                                 \
                (const __attribute__((address_space(1))) void*)gx,            \
                (__attribute__((address_space(3))) void*)&xbuf[bufi][row*CK], \
                16, 0, 0);                                                    \
        }                                                                     \
    }

    #define QKV_COMPUTE(bufi)                                                 \
    {                                                                         \
        float4 wv0 = *(const float4*)&wbuf[bufi][(4*wave + 0)*CK + lane*4];   \
        float4 wv1 = *(const float4*)&wbuf[bufi][(4*wave + 1)*CK + lane*4];   \
        float4 wv2 = *(const float4*)&wbuf[bufi][(4*wave + 2)*CK + lane*4];   \
        float4 wv3 = *(const float4*)&wbuf[bufi][(4*wave + 3)*CK + lane*4];   \
        _Pragma("unroll")                                                     \
        for (int b = 0; b < 16; ++b) {                                        \
            float4 xv = *(const float4*)&xbuf[bufi][b * CK + lane * 4];       \
            acc[0][b] = fmaf(wv0.x, xv.x, acc[0][b]);                         \
            acc[0][b] = fmaf(wv0.y, xv.y, acc[0][b]);                         \
            acc[0][b] = fmaf(wv0.z, xv.z, acc[0][b]);                         \
            acc[0][b] = fmaf(wv0.w, xv.w, acc[0][b]);                         \
            acc[1][b] = fmaf(wv1.x, xv.x, acc[1][b]);                         \
            acc[1][b] = fmaf(wv1.y, xv.y, acc[1][b]);                         \
            acc[1][b] = fmaf(wv1.z, xv.z, acc[1][b]);                         \
            acc[1][b] = fmaf(wv1.w, xv.w, acc[1][b]);                         \
            acc[2][b] = fmaf(wv2.x, xv.x, acc[2][b]);                         \
            acc[2][b] = fmaf(wv2.y, xv.y, acc[2][b]);                         \
            acc[2][b] = fmaf(wv2.z, xv.z, acc[2][b]);                         \
            acc[2][b] = fmaf(wv2.w, xv.w, acc[2][b]);                         \
            acc[3][b] = fmaf(wv3.x, xv.x, acc[3][b]);                         \
            acc[3][b] = fmaf(wv3.y, xv.y, acc[3][b]);                         \
            acc[3][b] = fmaf(wv3.z, xv.z, acc[3][b]);                         \
            acc[3][b] = fmaf(wv3.w, xv.w, acc[3][b]);                         \
        }                                                                     \
    }

    // prologue: prefetch tiles 0,1,2 (24 DMAs outstanding)
    QKV_STAGE(0, 0);
    QKV_STAGE(1, 1);
    QKV_STAGE(2, 2);

    #pragma unroll 1
    for (int c = 0; c < NCHUNK; ++c) {
        if (c + 3 < NCHUNK) QKV_STAGE((c + 3) & (NB - 1), c + 3);
        // retire exactly the oldest tile (c): counted vmcnt, never 0 mid-loop
        const int ahead = (NCHUNK - 1) - c;
        if (ahead >= 3)      asm volatile("s_waitcnt vmcnt(24)" ::: "memory");
        else if (ahead == 2) asm volatile("s_waitcnt vmcnt(16)" ::: "memory");
        else if (ahead == 1) asm volatile("s_waitcnt vmcnt(8)"  ::: "memory");
        else                 asm volatile("s_waitcnt vmcnt(0)"  ::: "memory");
        __builtin_amdgcn_s_barrier();   // all waves' tile-c DMAs visible
        QKV_COMPUTE(c & (NB - 1));
        __builtin_amdgcn_s_barrier();   // tile-c buffer free for re-stage
    }
    #undef QKV_STAGE
    #undef QKV_COMPUTE

    // cross-lane reduction; lane (r*16+b) writes output (b, o0+4*wave+r)
    #pragma unroll
    for (int r = 0; r < 4; ++r) {
        #pragma unroll
        for (int b = 0; b < 16; ++b) {
            float s = acc[r][b];
            #pragma unroll
            for (int off = 32; off; off >>= 1) s += __shfl_xor(s, off, 64);
            if (lane == r * 16 + b)
                out[(size_t)b * S + o0 + 4 * wave + r]
                    = s + bias[o0 + 4 * wave + r];
        }
    }
}

// ---------------------------------------------------------------------------
// DIAGNOSTIC PROBE: copy-kernel-shaped pure stream of all of Wq/Wk/Wv
// (192 MB). 2048 blocks x 256 thr (~32 waves/CU), grid-stride float4,
// trivial VGPR. Measures achievable W-stream BW independent of GEMM
// structure (methodology rule #10: bench a known-good pattern).
// ---------------------------------------------------------------------------
__global__ __launch_bounds__(256) void wstream_probe(
    const float* __restrict__ Wq, const float* __restrict__ Wk,
    const float* __restrict__ Wv, float* __restrict__ sink)
{
    const size_t nthr = (size_t)gridDim.x * 256;
    const size_t tid  = (size_t)blockIdx.x * 256 + threadIdx.x;
    const size_t n4   = (size_t)S * S / 4;      // float4s per matrix
    float sx = 0.f, sy = 0.f, sz = 0.f, sw = 0.f;

    const float4* A = (const float4*)Wq;
    const float4* Bm = (const float4*)Wk;
    const float4* C = (const float4*)Wv;
    #pragma unroll 1
    for (size_t i = tid; i < n4; i += nthr) {
        float4 a = A[i];
        sx += a.x; sy += a.y; sz += a.z; sw += a.w;
    }
    #pragma unroll 1
    for (size_t i = tid; i < n4; i += nthr) {
        float4 a = Bm[i];
        sx += a.x; sy += a.y; sz += a.z; sw += a.w;
    }
    #pragma unroll 1
    for (size_t i = tid; i < n4; i += nthr) {
        float4 a = C[i];
        sx += a.x; sy += a.y; sz += a.z; sw += a.w;
    }
    float s = sx + sy + sz + sw;
    #pragma unroll
    for (int off = 32; off; off >>= 1) s += __shfl_xor(s, off, 64);
    if ((threadIdx.x & 63) == 0)
        sink[(blockIdx.x * 4) + (threadIdx.x >> 6)] = s;
}

// ---------------------------------------------------------------------------
// Inclusive prefix max/min of k per batch row. 16 blocks x 256 threads.
// ---------------------------------------------------------------------------
__global__ __launch_bounds__(256) void scan_kernel(
    const float* __restrict__ k,
    float* __restrict__ rmax, float* __restrict__ rmin)
{
    __shared__ float smax[256], smin[256];
    const int b = blockIdx.x, t = threadIdx.x;
    const float* kb = k + b * S;

    float seg[16];
    float lmax = -INFINITY, lmin = INFINITY;
    #pragma unroll
    for (int e = 0; e < 16; ++e) {
        seg[e] = kb[t * 16 + e];
        lmax = fmaxf(lmax, seg[e]);
        lmin = fminf(lmin, seg[e]);
    }
    smax[t] = lmax; smin[t] = lmin;
    __syncthreads();
    for (int off = 1; off < 256; off <<= 1) {
        float vx = (t >= off) ? smax[t - off] : -INFINITY;
        float vn = (t >= off) ? smin[t - off] :  INFINITY;
        __syncthreads();
        smax[t] = fmaxf(smax[t], vx);
        smin[t] = fminf(smin[t], vn);
        __syncthreads();
    }
    float runmax = (t > 0) ? smax[t - 1] : -INFINITY;
    float runmin = (t > 0) ? smin[t - 1] :  INFINITY;
    #pragma unroll
    for (int e = 0; e < 16; ++e) {
        runmax = fmaxf(runmax, seg[e]);
        runmin = fminf(runmin, seg[e]);
        rmax[b * S + t * 16 + e] = runmax;
        rmin[b * S + t * 16 + e] = runmin;
    }
}

// ---------------------------------------------------------------------------
// d=1 causal attention, single pass (row max known from prefix scan).
// Wave handles R=8 consecutive rows of one batch, sharing k/v loads.
// ---------------------------------------------------------------------------
__global__ __launch_bounds__(256) void attn_kernel(
    const float* __restrict__ q, const float* __restrict__ k,
    const float* __restrict__ v,
    const float* __restrict__ rmax, const float* __restrict__ rmin,
    float* __restrict__ out)
{
    const int tid = threadIdx.x, lane = tid & 63, wave = tid >> 6;
    const int task = blockIdx.x * 4 + wave;     // 0..8191
    const int b    = task & 15;
    const int rbi  = task >> 4;                 // 0..511
    const int i0   = (511 - rbi) * R;           // descending: big rows first
    const float* kb = k + b * S;
    const float* vb = v + b * S;
    const float LOG2E = 1.4426950408889634f;

    float a[R], cc[R], den[R], num[R];
    #pragma unroll
    for (int r = 0; r < R; ++r) {
        float qi = q[b * S + i0 + r];
        float m  = (qi >= 0.f) ? qi * rmax[b * S + i0 + r]
                               : qi * rmin[b * S + i0 + r];
        a[r]  = qi * LOG2E;
        cc[r] = -m * LOG2E;
        den[r] = 0.f; num[r] = 0.f;
    }

    const int nfull = (i0 + 1) >> 8;            // full 256-wide chunks
    #pragma unroll 1
    for (int it = 0; it < nfull; ++it) {
        const int j = it * 256 + lane * 4;
        float4 k4 = *(const float4*)&kb[j];
        float4 v4 = *(const float4*)&vb[j];
        #pragma unroll
        for (int jj = 0; jj < 4; ++jj) {
            float kx = (&k4.x)[jj], vx = (&v4.x)[jj];
            #pragma unroll
            for (int r = 0; r < R; ++r) {
                float e = exp2f(fmaf(a[r], kx, cc[r]));
                den[r] += e;
                num[r] = fmaf(e, vx, num[r]);
            }
        }
    }
    // masked tail
    const int imax = i0 + R - 1;
    for (int j = nfull * 256 + lane; j <= imax; j += 64) {
        float kx = kb[j], vx = vb[j];
        #pragma unroll
        for (int r = 0; r < R; ++r) {
            float e = (j <= i0 + r) ? exp2f(fmaf(a[r], kx, cc[r])) : 0.f;
            den[r] += e;
            num[r] = fmaf(e, vx, num[r]);
        }
    }

    #pragma unroll
    for (int r = 0; r < R; ++r) {
        float d = den[r], n = num[r];
        #pragma unroll
        for (int off = 32; off; off >>= 1) {
            d += __shfl_xor(d, off, 64);
            n += __shfl_xor(n, off, 64);
        }
        if (lane == r) out[b * S + i0 + r] = n / d;
    }
}

extern "C" void kernel_launch(void* const* d_in, const int* in_sizes, int n_in,
                              void* d_out, int out_size, void* d_ws, size_t ws_size,
                              hipStream_t stream) {
    const float* x  = (const float*)d_in[0];
    const float* Wq = (const float*)d_in[1];
    const float* bq = (const float*)d_in[2];
    const float* Wk = (const float*)d_in[3];
    const float* bk = (const float*)d_in[4];
    const float* Wv = (const float*)d_in[5];
    const float* bv = (const float*)d_in[6];
    float* out = (float*)d_out;

    float* ws   = (float*)d_ws;
    float* q    = ws;                // 16*4096
    float* k    = ws + 65536;
    float* v    = ws + 131072;
    float* rmax = ws + 196608;
    float* rmin = ws + 262144;
    float* sink = ws + 327680;       // probe sink (32 KB)

    qkv_kernel<<<768, 256, 0, stream>>>(x, Wq, bq, Wk, bk, Wv, bv, q, k, v);
    scan_kernel<<<16, 256, 0, stream>>>(k, rmax, rmin);
    attn_kernel<<<2048, 256, 0, stream>>>(q, k, v, rmax, rmin, out);
    wstream_probe<<<2048, 256, 0, stream>>>(Wq, Wk, Wv, sink);
}

// Round 9
// 116.354 us; speedup vs baseline: 1.5632x; 1.5632x over previous
//
#include <hip/hip_runtime.h>
#include <math.h>

#define S 4096
#define B 16
#define R 8             // attention rows per wave

// ---------------------------------------------------------------------------
// Fused QKV skinny GEMM — probe-shaped: no LDS, no barriers, no prefetch.
// R8's probe measured 6.4 TB/s with exactly this shape (high TLP, direct
// loads, immediate consumption); every barriered/lockstep GEMM got 0.7-1.8.
// Theory: channel camping — all blocks sweeping columns in phase hit the
// same HBM channels (addresses congruent mod the 16KB row stride); barriers
// re-sync the sweep. Fix: per-block staggered column start (accumulation is
// order-independent), so concurrent blocks cover the full row period.
// Grid: 1536 blocks = 3 mats x 512 groups(8 rows); wave = 2 rows x 16 b.
// W float4 regs reused across both batch-halves -> W read once from HBM.
// ---------------------------------------------------------------------------
__global__ __launch_bounds__(256) void qkv_kernel(
    const float* __restrict__ x,
    const float* __restrict__ Wq, const float* __restrict__ bq,
    const float* __restrict__ Wk, const float* __restrict__ bk,
    const float* __restrict__ Wv, const float* __restrict__ bv,
    float* __restrict__ q, float* __restrict__ k, float* __restrict__ v)
{
    const int tid  = threadIdx.x;
    const int lane = tid & 63;
    const int wave = tid >> 6;
    const int bx   = blockIdx.x;        // 0..1535
    const int mat  = bx >> 9;           // 0:q 1:k 2:v
    const int og   = bx & 511;          // 8-row group

    const float* W    = (mat == 0) ? Wq : (mat == 1) ? Wk : Wv;
    const float* bias = (mat == 0) ? bq : (mat == 1) ? bk : bv;
    float*       out  = (mat == 0) ? q  : (mat == 1) ? k  : v;
    const int o0 = og * 8 + wave * 2;               // this wave's 2 W-rows
    const float* w0p = W + (size_t)o0 * S + lane * 4;
    const float* w1p = w0p + S;
    const float* xp  = x + lane * 4;

    // stagger column start per block: decorrelate HBM channel access
    const int cstart = ((og * 5) + mat) & 15;

    float acc[2][16];
    #pragma unroll
    for (int r = 0; r < 2; ++r)
        #pragma unroll
        for (int b = 0; b < 16; ++b) acc[r][b] = 0.f;

    #pragma unroll 1
    for (int ccc = 0; ccc < 16; ++ccc) {
        const int c   = (cstart + ccc) & 15;
        const int off = c * 256;
        float4 w0 = *(const float4*)&w0p[off];
        float4 w1 = *(const float4*)&w1p[off];
        float4 xa0 = *(const float4*)&xp[(size_t) 0 * S + off];
        float4 xa1 = *(const float4*)&xp[(size_t) 1 * S + off];
        float4 xa2 = *(const float4*)&xp[(size_t) 2 * S + off];
        float4 xa3 = *(const float4*)&xp[(size_t) 3 * S + off];
        float4 xa4 = *(const float4*)&xp[(size_t) 4 * S + off];
        float4 xa5 = *(const float4*)&xp[(size_t) 5 * S + off];
        float4 xa6 = *(const float4*)&xp[(size_t) 6 * S + off];
        float4 xa7 = *(const float4*)&xp[(size_t) 7 * S + off];

        #define FMA4(r, b, wv, xv)                       \
            acc[r][b] = fmaf(wv.x, xv.x, acc[r][b]);     \
            acc[r][b] = fmaf(wv.y, xv.y, acc[r][b]);     \
            acc[r][b] = fmaf(wv.z, xv.z, acc[r][b]);     \
            acc[r][b] = fmaf(wv.w, xv.w, acc[r][b]);

        FMA4(0, 0, w0, xa0)  FMA4(1, 0, w1, xa0)
        FMA4(0, 1, w0, xa1)  FMA4(1, 1, w1, xa1)
        FMA4(0, 2, w0, xa2)  FMA4(1, 2, w1, xa2)
        FMA4(0, 3, w0, xa3)  FMA4(1, 3, w1, xa3)
        FMA4(0, 4, w0, xa4)  FMA4(1, 4, w1, xa4)
        FMA4(0, 5, w0, xa5)  FMA4(1, 5, w1, xa5)
        FMA4(0, 6, w0, xa6)  FMA4(1, 6, w1, xa6)
        FMA4(0, 7, w0, xa7)  FMA4(1, 7, w1, xa7)

        // second batch-half reuses the SAME W registers (W read once)
        float4 xb0 = *(const float4*)&xp[(size_t) 8 * S + off];
        float4 xb1 = *(const float4*)&xp[(size_t) 9 * S + off];
        float4 xb2 = *(const float4*)&xp[(size_t)10 * S + off];
        float4 xb3 = *(const float4*)&xp[(size_t)11 * S + off];
        float4 xb4 = *(const float4*)&xp[(size_t)12 * S + off];
        float4 xb5 = *(const float4*)&xp[(size_t)13 * S + off];
        float4 xb6 = *(const float4*)&xp[(size_t)14 * S + off];
        float4 xb7 = *(const float4*)&xp[(size_t)15 * S + off];

        FMA4(0,  8, w0, xb0)  FMA4(1,  8, w1, xb0)
        FMA4(0,  9, w0, xb1)  FMA4(1,  9, w1, xb1)
        FMA4(0, 10, w0, xb2)  FMA4(1, 10, w1, xb2)
        FMA4(0, 11, w0, xb3)  FMA4(1, 11, w1, xb3)
        FMA4(0, 12, w0, xb4)  FMA4(1, 12, w1, xb4)
        FMA4(0, 13, w0, xb5)  FMA4(1, 13, w1, xb5)
        FMA4(0, 14, w0, xb6)  FMA4(1, 14, w1, xb6)
        FMA4(0, 15, w0, xb7)  FMA4(1, 15, w1, xb7)
        #undef FMA4
    }

    // cross-lane reduction; lane (r*16+b) writes output (b, o0+r)
    #pragma unroll
    for (int r = 0; r < 2; ++r) {
        #pragma unroll
        for (int b = 0; b < 16; ++b) {
            float s = acc[r][b];
            #pragma unroll
            for (int off = 32; off; off >>= 1) s += __shfl_xor(s, off, 64);
            if (lane == r * 16 + b)
                out[(size_t)b * S + o0 + r] = s + bias[o0 + r];
        }
    }
}

// ---------------------------------------------------------------------------
// Inclusive prefix max/min of k per batch row. 16 blocks x 256 threads.
// ---------------------------------------------------------------------------
__global__ __launch_bounds__(256) void scan_kernel(
    const float* __restrict__ k,
    float* __restrict__ rmax, float* __restrict__ rmin)
{
    __shared__ float smax[256], smin[256];
    const int b = blockIdx.x, t = threadIdx.x;
    const float* kb = k + b * S;

    float seg[16];
    float lmax = -INFINITY, lmin = INFINITY;
    #pragma unroll
    for (int e = 0; e < 16; ++e) {
        seg[e] = kb[t * 16 + e];
        lmax = fmaxf(lmax, seg[e]);
        lmin = fminf(lmin, seg[e]);
    }
    smax[t] = lmax; smin[t] = lmin;
    __syncthreads();
    for (int off = 1; off < 256; off <<= 1) {
        float vx = (t >= off) ? smax[t - off] : -INFINITY;
        float vn = (t >= off) ? smin[t - off] :  INFINITY;
        __syncthreads();
        smax[t] = fmaxf(smax[t], vx);
        smin[t] = fminf(smin[t], vn);
        __syncthreads();
    }
    float runmax = (t > 0) ? smax[t - 1] : -INFINITY;
    float runmin = (t > 0) ? smin[t - 1] :  INFINITY;
    #pragma unroll
    for (int e = 0; e < 16; ++e) {
        runmax = fmaxf(runmax, seg[e]);
        runmin = fminf(runmin, seg[e]);
        rmax[b * S + t * 16 + e] = runmax;
        rmin[b * S + t * 16 + e] = runmin;
    }
}

// ---------------------------------------------------------------------------
// d=1 causal attention, single pass (row max known from prefix scan).
// Wave handles R=8 consecutive rows of one batch, sharing k/v loads.
// ---------------------------------------------------------------------------
__global__ __launch_bounds__(256) void attn_kernel(
    const float* __restrict__ q, const float* __restrict__ k,
    const float* __restrict__ v,
    const float* __restrict__ rmax, const float* __restrict__ rmin,
    float* __restrict__ out)
{
    const int tid = threadIdx.x, lane = tid & 63, wave = tid >> 6;
    const int task = blockIdx.x * 4 + wave;     // 0..8191
    const int b    = task & 15;
    const int rbi  = task >> 4;                 // 0..511
    const int i0   = (511 - rbi) * R;           // descending: big rows first
    const float* kb = k + b * S;
    const float* vb = v + b * S;
    const float LOG2E = 1.4426950408889634f;

    float a[R], cc[R], den[R], num[R];
    #pragma unroll
    for (int r = 0; r < R; ++r) {
        float qi = q[b * S + i0 + r];
        float m  = (qi >= 0.f) ? qi * rmax[b * S + i0 + r]
                               : qi * rmin[b * S + i0 + r];
        a[r]  = qi * LOG2E;
        cc[r] = -m * LOG2E;
        den[r] = 0.f; num[r] = 0.f;
    }

    const int nfull = (i0 + 1) >> 8;            // full 256-wide chunks
    #pragma unroll 1
    for (int it = 0; it < nfull; ++it) {
        const int j = it * 256 + lane * 4;
        float4 k4 = *(const float4*)&kb[j];
        float4 v4 = *(const float4*)&vb[j];
        #pragma unroll
        for (int jj = 0; jj < 4; ++jj) {
            float kx = (&k4.x)[jj], vx = (&v4.x)[jj];
            #pragma unroll
            for (int r = 0; r < R; ++r) {
                float e = exp2f(fmaf(a[r], kx, cc[r]));
                den[r] += e;
                num[r] = fmaf(e, vx, num[r]);
            }
        }
    }
    // masked tail
    const int imax = i0 + R - 1;
    for (int j = nfull * 256 + lane; j <= imax; j += 64) {
        float kx = kb[j], vx = vb[j];
        #pragma unroll
        for (int r = 0; r < R; ++r) {
            float e = (j <= i0 + r) ? exp2f(fmaf(a[r], kx, cc[r])) : 0.f;
            den[r] += e;
            num[r] = fmaf(e, vx, num[r]);
        }
    }

    #pragma unroll
    for (int r = 0; r < R; ++r) {
        float d = den[r], n = num[r];
        #pragma unroll
        for (int off = 32; off; off >>= 1) {
            d += __shfl_xor(d, off, 64);
            n += __shfl_xor(n, off, 64);
        }
        if (lane == r) out[b * S + i0 + r] = n / d;
    }
}

extern "C" void kernel_launch(void* const* d_in, const int* in_sizes, int n_in,
                              void* d_out, int out_size, void* d_ws, size_t ws_size,
                              hipStream_t stream) {
    const float* x  = (const float*)d_in[0];
    const float* Wq = (const float*)d_in[1];
    const float* bq = (const float*)d_in[2];
    const float* Wk = (const float*)d_in[3];
    const float* bk = (const float*)d_in[4];
    const float* Wv = (const float*)d_in[5];
    const float* bv = (const float*)d_in[6];
    float* out = (float*)d_out;

    float* ws   = (float*)d_ws;
    float* q    = ws;                // 16*4096
    float* k    = ws + 65536;
    float* v    = ws + 131072;
    float* rmax = ws + 196608;
    float* rmin = ws + 262144;       // total 1.25 MB scratch

    qkv_kernel<<<1536, 256, 0, stream>>>(x, Wq, bq, Wk, bk, Wv, bv, q, k, v);
    scan_kernel<<<16, 256, 0, stream>>>(k, rmax, rmin);
    attn_kernel<<<2048, 256, 0, stream>>>(q, k, v, rmax, rmin, out);
}